// Round 4
// baseline (992.228 us; speedup 1.0000x reference)
//
#include <hip/hip_runtime.h>
#include <hip/hip_bf16.h>
#include <stdint.h>
#include <math.h>

#define T_TOK 4096
#define HD    1024
#define NE    16
#define FF    2816
#define TOPK  8
#define NPAIR (T_TOK*TOPK)

typedef __attribute__((ext_vector_type(8))) __bf16 bf16x8;
typedef __attribute__((ext_vector_type(4))) float  f32x4;

__device__ __forceinline__ unsigned short f2bf(float x){
  union { float f; unsigned u; } c; c.f = x;
  unsigned r = (c.u + 0x7FFFu + ((c.u >> 16) & 1u)) >> 16;
  return (unsigned short)r;
}
__device__ __forceinline__ float bf2f(unsigned short h){
  union { unsigned u; float f; } c; c.u = ((unsigned)h) << 16; return c.f;
}

__device__ __forceinline__ void gload16(const void* src, void* lds_dst){
  __builtin_amdgcn_global_load_lds((const __attribute__((address_space(1))) unsigned int*)src,
                                   (__attribute__((address_space(3))) unsigned int*)lds_dst,
                                   16, 0, 0);
}

// ---------------- fp32 -> bf16 (RNE) ----------------
__global__ __launch_bounds__(256) void convert_bf16_kernel(
    const float* __restrict__ src, unsigned short* __restrict__ dst, int n4)
{
  int i = blockIdx.x * blockDim.x + threadIdx.x;
  int stride = gridDim.x * blockDim.x;
  for (; i < n4; i += stride){
    float4 v = ((const float4*)src)[i];
    ushort4 o;
    o.x = f2bf(v.x); o.y = f2bf(v.y); o.z = f2bf(v.z); o.w = f2bf(v.w);
    ((ushort4*)dst)[i] = o;
  }
}

// ---------------- router ----------------
__global__ __launch_bounds__(256) void router_kernel(
    const float* __restrict__ x, const float* __restrict__ rw,
    unsigned short* __restrict__ xbf, int* __restrict__ topk_idx, float* __restrict__ topk_w)
{
  __shared__ float xs[HD];
  __shared__ float lg[NE];
  const int t   = blockIdx.x;
  const int tid = threadIdx.x;
  const int lane = tid & 63;
  const int wid  = tid >> 6;

  float4 v = ((const float4*)(x + (size_t)t*HD))[tid];
  ((float4*)xs)[tid] = v;
  ushort4 o;
  o.x = f2bf(v.x); o.y = f2bf(v.y); o.z = f2bf(v.z); o.w = f2bf(v.w);
  ((ushort4*)(xbf + (size_t)t*HD))[tid] = o;
  __syncthreads();

  for (int ee = 0; ee < 4; ++ee){
    int e = wid*4 + ee;
    const float* w = rw + (size_t)e*HD;
    float p = 0.f;
    for (int j = lane; j < HD; j += 64) p += xs[j] * w[j];
    #pragma unroll
    for (int offs = 32; offs; offs >>= 1) p += __shfl_xor(p, offs, 64);
    if (lane == 0) lg[e] = p;
  }
  __syncthreads();

  if (tid == 0){
    float vals[NE];
    #pragma unroll
    for (int e = 0; e < NE; ++e) vals[e] = lg[e];
    int   idx[TOPK]; float tv[TOPK];
    for (int k = 0; k < TOPK; ++k){
      int bi = 0; float bv = -3.4e38f;
      for (int e = 0; e < NE; ++e) if (vals[e] > bv){ bv = vals[e]; bi = e; }
      idx[k] = bi; tv[k] = bv; vals[bi] = -3.4e38f;
    }
    float m = tv[0];
    float ex[TOPK]; float s = 0.f;
    for (int k = 0; k < TOPK; ++k){ ex[k] = expf(tv[k] - m); s += ex[k]; }
    float inv = 1.f / s;
    for (int k = 0; k < TOPK; ++k){
      topk_idx[t*TOPK + k] = idx[k];
      topk_w [t*TOPK + k] = ex[k] * inv;
    }
  }
}

// ---------------- per-expert counts ----------------
__global__ __launch_bounds__(256) void count_kernel(
    const int* __restrict__ topk_idx, int* __restrict__ cnt)
{
  const int e = blockIdx.x;
  const int tid = threadIdx.x;
  __shared__ int wc[4];
  int c = 0;
  for (int t = tid; t < T_TOK; t += 256){
    bool f = false;
    #pragma unroll
    for (int k = 0; k < TOPK; ++k) f |= (topk_idx[t*TOPK + k] == e);
    c += f ? 1 : 0;
  }
  #pragma unroll
  for (int offs = 32; offs; offs >>= 1) c += __shfl_xor(c, offs, 64);
  if ((tid & 63) == 0) wc[tid >> 6] = c;
  __syncthreads();
  if (tid == 0) cnt[e] = wc[0] + wc[1] + wc[2] + wc[3];
}

// ---------------- deterministic token lists ----------------
__global__ __launch_bounds__(256) void lists_kernel(
    const int* __restrict__ topk_idx, const int* __restrict__ cnt,
    int* __restrict__ rows, int* __restrict__ slot_of, int* __restrict__ offs_out)
{
  const int e = blockIdx.x;
  const int tid = threadIdx.x;
  const int lane = tid & 63;
  const int wid  = tid >> 6;
  int off = 0;
  for (int i = 0; i < e; ++i) off += cnt[i];
  if (tid == 0) offs_out[e] = off;

  __shared__ int wc[4];
  int base = 0;
  for (int c0 = 0; c0 < T_TOK; c0 += 256){
    int t = c0 + tid;
    int kpos = -1;
    #pragma unroll
    for (int k = 0; k < TOPK; ++k) if (topk_idx[t*TOPK + k] == e) kpos = k;
    bool f = (kpos >= 0);
    unsigned long long m = __ballot(f);
    if (lane == 0) wc[wid] = __popcll(m);
    __syncthreads();
    int p = base;
    for (int w = 0; w < wid; ++w) p += wc[w];
    p += __popcll(m & ((1ULL << lane) - 1ULL));
    if (f){
      rows[off + p] = t;
      slot_of[t*TOPK + kpos] = off + p;
    }
    int tot = wc[0] + wc[1] + wc[2] + wc[3];
    __syncthreads();
    base += tot;
  }
}

// ======================= 8-phase grouped GEMMs =======================
// Common: 512 threads (8 waves, 2M x 4N), BK=64, double-buffered 128KB dynamic
// LDS, T2 XOR swizzle (phys 16B-slot = logical ^ (row&7), pre-swizzled source),
// counted vmcnt(4) at phases 4/8 only, raw s_barrier, setprio around MFMA.

#define BARW() do { \
    __builtin_amdgcn_s_barrier(); \
    asm volatile("s_waitcnt lgkmcnt(0)" ::: "memory"); \
    __builtin_amdgcn_sched_barrier(0); \
  } while(0)
#define ENDPH() __builtin_amdgcn_s_barrier()
#define VMC4()  asm volatile("s_waitcnt vmcnt(4)" ::: "memory")

// ---------------- stage-1: h = silu(x@gateT)*(x@upT) ----------------
// BM=256 tokens x BN=128 F-cols, fused gate+up.
// LDS shorts: A [0,32768)=2buf x 256 x 64 ; Bg [32768,49152) ; Bu [49152,65536)
// halves: 0=A-lo 1=Bg 2=A-hi 3=Bu. phases: g-lo, u-lo, g-hi, u-hi.
__global__ __launch_bounds__(512, 2) void gemm_gateup8(
    const unsigned short* __restrict__ xbf,
    const unsigned short* __restrict__ gw,
    const unsigned short* __restrict__ uw,
    const int* __restrict__ rows, const int* __restrict__ cnt, const int* __restrict__ offs,
    unsigned short* __restrict__ hbuf)
{
  extern __shared__ unsigned short sm[];
  constexpr int NT = HD/64;   // 16
  const int cpx = gridDim.x >> 3;
  const int bid = blockIdx.x;
  const int nid = (bid & 7) * cpx + (bid >> 3);
  const int mb   = nid & 15;
  const int rest = nid >> 4;
  const int nb   = rest % (FF/128);
  const int e    = rest / (FF/128);

  const int cN = cnt[e];
  const int m0 = mb * 256;
  if (m0 >= cN) return;
  const int n0 = nb * 128;
  const int off_e = offs[e];

  const int tid  = threadIdx.x;
  const int lane = tid & 63;
  const int wid  = tid >> 6;
  const int ar = lane & 15;
  const int kb = lane >> 4;
  const int wrow = (wid >> 2) * 128;
  const int wcol = (wid & 3) * 32;

  const unsigned short* pA[2][2];
  #pragma unroll
  for (int H = 0; H < 2; ++H){
    #pragma unroll
    for (int j = 0; j < 2; ++j){
      int c = j*512 + tid;
      int r = c >> 3, s = c & 7;
      int rm = m0 + H*128 + r; if (rm > cN-1) rm = cN-1;
      pA[H][j] = xbf + (size_t)rows[off_e + rm]*HD + ((s ^ (r & 7))*8);
    }
  }
  const unsigned short* pBg[2];
  const unsigned short* pBu[2];
  #pragma unroll
  for (int j = 0; j < 2; ++j){
    int c = j*512 + tid;
    int r = c >> 3, s = c & 7;
    pBg[j] = gw + ((size_t)e*FF + n0 + r)*HD + ((s ^ (r & 7))*8);
    pBu[j] = uw + ((size_t)e*FF + n0 + r)*HD + ((s ^ (r & 7))*8);
  }

  #define ST_HALF1(hh, T) do { \
    int tt = (T) > NT-1 ? NT-1 : (T); \
    int bb_ = (T) & 1; \
    if ((hh) == 0){ gload16(pA[0][0] + tt*64, &sm[bb_*16384 + tid*8]); \
                    gload16(pA[0][1] + tt*64, &sm[bb_*16384 + 4096 + tid*8]); } \
    else if ((hh) == 1){ gload16(pBg[0] + tt*64, &sm[32768 + bb_*8192 + tid*8]); \
                         gload16(pBg[1] + tt*64, &sm[32768 + bb_*8192 + 4096 + tid*8]); } \
    else if ((hh) == 2){ gload16(pA[1][0] + tt*64, &sm[bb_*16384 + 8192 + tid*8]); \
                         gload16(pA[1][1] + tt*64, &sm[bb_*16384 + 12288 + tid*8]); } \
    else { gload16(pBu[0] + tt*64, &sm[49152 + bb_*8192 + tid*8]); \
           gload16(pBu[1] + tt*64, &sm[49152 + bb_*8192 + 4096 + tid*8]); } \
  } while(0)

  f32x4 accg[8][2] = {};
  f32x4 accu[8][2] = {};
  bf16x8 pa[4][2], pg[2][2], pu[2][2];

  #define DSRA1(B, mh) { _Pragma("unroll") for (int fm=0; fm<4; ++fm){ int r = wrow + (mh)*64 + fm*16 + ar; \
      _Pragma("unroll") for (int kk=0; kk<2; ++kk) pa[fm][kk] = *(const bf16x8*)&sm[(B)*16384 + r*64 + (((kk*4+kb) ^ (r & 7))*8)]; } }
  #define DSRG1(B) { _Pragma("unroll") for (int fn=0; fn<2; ++fn){ int r = wcol + fn*16 + ar; \
      _Pragma("unroll") for (int kk=0; kk<2; ++kk) pg[fn][kk] = *(const bf16x8*)&sm[32768 + (B)*8192 + r*64 + (((kk*4+kb) ^ (r & 7))*8)]; } }
  #define DSRU1(B) { _Pragma("unroll") for (int fn=0; fn<2; ++fn){ int r = wcol + fn*16 + ar; \
      _Pragma("unroll") for (int kk=0; kk<2; ++kk) pu[fn][kk] = *(const bf16x8*)&sm[49152 + (B)*8192 + r*64 + (((kk*4+kb) ^ (r & 7))*8)]; } }
  #define MFMA1(ACC, PB, mh) { \
    __builtin_amdgcn_s_setprio(1); \
    _Pragma("unroll") for (int kk=0; kk<2; ++kk) \
      _Pragma("unroll") for (int fm=0; fm<4; ++fm) \
        _Pragma("unroll") for (int fn=0; fn<2; ++fn) \
          ACC[(mh)*4+fm][fn] = __builtin_amdgcn_mfma_f32_16x16x32_bf16(pa[fm][kk], PB[fn][kk], ACC[(mh)*4+fm][fn], 0,0,0); \
    __builtin_amdgcn_s_setprio(0); }

  // prologue: tile0 all 4 halves, tile1 halves 0,1
  ST_HALF1(0,0); ST_HALF1(1,0); ST_HALF1(2,0); ST_HALF1(3,0);
  ST_HALF1(0,1); ST_HALF1(1,1);
  VMC4();
  __builtin_amdgcn_s_barrier();

  for (int it = 0; it < NT/2; ++it){
    const int t = 2*it;
    // ---- tile t (buf 0) ----
    DSRA1(0,0); DSRG1(0);          // ph1: g-lo
    ST_HALF1(2, t+1);
    BARW();
    MFMA1(accg, pg, 0);
    ENDPH();
    DSRU1(0);                      // ph2: u-lo (carry pa)
    ST_HALF1(3, t+1);
    BARW();
    MFMA1(accu, pu, 0);
    ENDPH();
    DSRA1(0,1);                    // ph3: g-hi (carry pg)
    ST_HALF1(0, t+2);
    BARW();
    MFMA1(accg, pg, 1);
    ENDPH();
    ST_HALF1(1, t+2);              // ph4: u-hi (carry pa, pu)
    VMC4();
    BARW();
    MFMA1(accu, pu, 1);
    ENDPH();
    // ---- tile t+1 (buf 1) ----
    DSRA1(1,0); DSRG1(1);          // ph5
    ST_HALF1(2, t+2);
    BARW();
    MFMA1(accg, pg, 0);
    ENDPH();
    DSRU1(1);                      // ph6
    ST_HALF1(3, t+2);
    BARW();
    MFMA1(accu, pu, 0);
    ENDPH();
    DSRA1(1,1);                    // ph7
    ST_HALF1(0, t+3);
    BARW();
    MFMA1(accg, pg, 1);
    ENDPH();
    ST_HALF1(1, t+3);              // ph8
    VMC4();
    BARW();
    MFMA1(accu, pu, 1);
    ENDPH();
  }
  asm volatile("s_waitcnt vmcnt(0)" ::: "memory");

  #pragma unroll
  for (int m = 0; m < 8; ++m){
    int gm = m0 + wrow + m*16 + kb*4;
    #pragma unroll
    for (int n = 0; n < 2; ++n){
      int fcol = n0 + wcol + n*16 + ar;
      #pragma unroll
      for (int i = 0; i < 4; ++i){
        int r = gm + i;
        if (r < cN){
          float g = accg[m][n][i];
          float u = accu[m][n][i];
          float s = g / (1.0f + expf(-g));
          hbuf[(size_t)(off_e + r)*FF + fcol] = f2bf(s * u);
        }
      }
    }
  }
}

// ---------------- stage-2: y = h @ downT ----------------
// BM=256 x BN=256. LDS shorts: A [0,32768) ; B [32768,65536), each 2buf x 256 x 64.
// halves: 0=A-lo 1=B-lo 2=A-hi 3=B-hi. phases: (mlo,nlo),(mlo,nhi),(mhi,nlo),(mhi,nhi).
__global__ __launch_bounds__(512, 2) void gemm_down8(
    const unsigned short* __restrict__ hbuf,
    const unsigned short* __restrict__ dw,
    const int* __restrict__ cnt, const int* __restrict__ offs,
    unsigned short* __restrict__ ybuf)
{
  extern __shared__ unsigned short sm[];
  constexpr int NT = FF/64;   // 44
  const int cpx = gridDim.x >> 3;
  const int bid = blockIdx.x;
  const int nid = (bid & 7) * cpx + (bid >> 3);
  const int mb   = nid & 15;
  const int rest = nid >> 4;
  const int nb   = rest & 3;
  const int e    = rest >> 2;

  const int cN = cnt[e];
  const int m0 = mb * 256;
  if (m0 >= cN) return;
  const int n0 = nb * 256;
  const int off_e = offs[e];

  const int tid  = threadIdx.x;
  const int lane = tid & 63;
  const int wid  = tid >> 6;
  const int ar = lane & 15;
  const int kb = lane >> 4;
  const int wrow = (wid >> 2) * 128;
  const int wcol = (wid & 3) * 64;

  const unsigned short* pA[2][2];
  const unsigned short* pB[2][2];
  #pragma unroll
  for (int H = 0; H < 2; ++H){
    #pragma unroll
    for (int j = 0; j < 2; ++j){
      int c = j*512 + tid;
      int r = c >> 3, s = c & 7;
      int sw = (s ^ (r & 7))*8;
      int rm = m0 + H*128 + r; if (rm > cN-1) rm = cN-1;
      pA[H][j] = hbuf + (size_t)(off_e + rm)*FF + sw;
      pB[H][j] = dw + ((size_t)e*HD + n0 + H*128 + r)*FF + sw;
    }
  }

  #define ST_HALF2(hh, T) do { \
    int tt = (T) > NT-1 ? NT-1 : (T); \
    int bb_ = (T) & 1; \
    if ((hh) == 0){ gload16(pA[0][0] + tt*64, &sm[bb_*16384 + tid*8]); \
                    gload16(pA[0][1] + tt*64, &sm[bb_*16384 + 4096 + tid*8]); } \
    else if ((hh) == 1){ gload16(pB[0][0] + tt*64, &sm[32768 + bb_*16384 + tid*8]); \
                         gload16(pB[0][1] + tt*64, &sm[32768 + bb_*16384 + 4096 + tid*8]); } \
    else if ((hh) == 2){ gload16(pA[1][0] + tt*64, &sm[bb_*16384 + 8192 + tid*8]); \
                         gload16(pA[1][1] + tt*64, &sm[bb_*16384 + 12288 + tid*8]); } \
    else { gload16(pB[1][0] + tt*64, &sm[32768 + bb_*16384 + 8192 + tid*8]); \
           gload16(pB[1][1] + tt*64, &sm[32768 + bb_*16384 + 12288 + tid*8]); } \
  } while(0)

  f32x4 acc[8][4] = {};
  bf16x8 pa[4][2], pbl[2][2], pbh[2][2];

  #define DSRA2(B, mh) { _Pragma("unroll") for (int fm=0; fm<4; ++fm){ int r = wrow + (mh)*64 + fm*16 + ar; \
      _Pragma("unroll") for (int kk=0; kk<2; ++kk) pa[fm][kk] = *(const bf16x8*)&sm[(B)*16384 + r*64 + (((kk*4+kb) ^ (r & 7))*8)]; } }
  #define DSRB2(B, nh, PB) { _Pragma("unroll") for (int fn=0; fn<2; ++fn){ int r = wcol + (nh)*32 + fn*16 + ar; \
      _Pragma("unroll") for (int kk=0; kk<2; ++kk) PB[fn][kk] = *(const bf16x8*)&sm[32768 + (B)*16384 + r*64 + (((kk*4+kb) ^ (r & 7))*8)]; } }
  #define MFMA2(mh, nh, PB) { \
    __builtin_amdgcn_s_setprio(1); \
    _Pragma("unroll") for (int kk=0; kk<2; ++kk) \
      _Pragma("unroll") for (int fm=0; fm<4; ++fm) \
        _Pragma("unroll") for (int fn=0; fn<2; ++fn) \
          acc[(mh)*4+fm][(nh)*2+fn] = __builtin_amdgcn_mfma_f32_16x16x32_bf16(pa[fm][kk], PB[fn][kk], acc[(mh)*4+fm][(nh)*2+fn], 0,0,0); \
    __builtin_amdgcn_s_setprio(0); }

  ST_HALF2(0,0); ST_HALF2(1,0); ST_HALF2(2,0); ST_HALF2(3,0);
  ST_HALF2(0,1); ST_HALF2(1,1);
  VMC4();
  __builtin_amdgcn_s_barrier();

  for (int it = 0; it < NT/2; ++it){
    const int t = 2*it;
    // ---- tile t (buf 0) ----
    DSRA2(0,0); DSRB2(0,0,pbl);    // ph1
    ST_HALF2(2, t+1);
    BARW();
    MFMA2(0,0,pbl);
    ENDPH();
    DSRB2(0,1,pbh);                // ph2 (carry pa)
    ST_HALF2(3, t+1);
    BARW();
    MFMA2(0,1,pbh);
    ENDPH();
    DSRA2(0,1);                    // ph3 (carry pbl)
    ST_HALF2(0, t+2);
    BARW();
    MFMA2(1,0,pbl);
    ENDPH();
    ST_HALF2(1, t+2);              // ph4 (carry pa, pbh)
    VMC4();
    BARW();
    MFMA2(1,1,pbh);
    ENDPH();
    // ---- tile t+1 (buf 1) ----
    DSRA2(1,0); DSRB2(1,0,pbl);    // ph5
    ST_HALF2(2, t+2);
    BARW();
    MFMA2(0,0,pbl);
    ENDPH();
    DSRB2(1,1,pbh);                // ph6
    ST_HALF2(3, t+2);
    BARW();
    MFMA2(0,1,pbh);
    ENDPH();
    DSRA2(1,1);                    // ph7
    ST_HALF2(0, t+3);
    BARW();
    MFMA2(1,0,pbl);
    ENDPH();
    ST_HALF2(1, t+3);              // ph8
    VMC4();
    BARW();
    MFMA2(1,1,pbh);
    ENDPH();
  }
  asm volatile("s_waitcnt vmcnt(0)" ::: "memory");

  #pragma unroll
  for (int m = 0; m < 8; ++m){
    int gm = m0 + wrow + m*16 + kb*4;
    #pragma unroll
    for (int n = 0; n < 4; ++n){
      int col = n0 + wcol + (n>>1)*32 + (n&1)*16 + ar;
      #pragma unroll
      for (int i = 0; i < 4; ++i){
        int r = gm + i;
        if (r < cN){
          ybuf[(size_t)(off_e + r)*HD + col] = f2bf(acc[m][n][i]);
        }
      }
    }
  }
}

// ---------------- combine ----------------
__global__ __launch_bounds__(256) void combine_kernel(
    const unsigned short* __restrict__ ybuf,
    const int* __restrict__ slot_of, const float* __restrict__ topk_w,
    float* __restrict__ out)
{
  const int t   = blockIdx.x;
  const int tid = threadIdx.x;
  const int c0  = tid * 4;
  float4 acc = {0.f, 0.f, 0.f, 0.f};
  #pragma unroll
  for (int k = 0; k < TOPK; ++k){
    int slot = slot_of[t*TOPK + k];
    float w  = topk_w[t*TOPK + k];
    ushort4 v = *(const ushort4*)&ybuf[(size_t)slot*HD + c0];
    acc.x += w * bf2f(v.x);
    acc.y += w * bf2f(v.y);
    acc.z += w * bf2f(v.z);
    acc.w += w * bf2f(v.w);
  }
  ((float4*)out)[(size_t)t*(HD/4) + tid] = acc;
}

extern "C" void kernel_launch(void* const* d_in, const int* in_sizes, int n_in,
                              void* d_out, int out_size, void* d_ws, size_t ws_size,
                              hipStream_t stream)
{
  const float* x  = (const float*)d_in[0];
  const float* rw = (const float*)d_in[1];
  const float* gw = (const float*)d_in[2];
  const float* uw = (const float*)d_in[3];
  const float* dw = (const float*)d_in[4];
  float* out = (float*)d_out;

  char* ws = (char*)d_ws;
  size_t off = 0;
  auto alloc = [&](size_t b) -> void* {
    void* p = ws + off;
    off += (b + 255) & ~(size_t)255;
    return p;
  };

  unsigned short* gwb  = (unsigned short*)alloc((size_t)NE*FF*HD*2);
  unsigned short* uwb  = (unsigned short*)alloc((size_t)NE*FF*HD*2);
  unsigned short* dwb  = (unsigned short*)alloc((size_t)NE*HD*FF*2);
  unsigned short* xbf  = (unsigned short*)alloc((size_t)T_TOK*HD*2);
  unsigned short* hbuf = (unsigned short*)alloc((size_t)NPAIR*FF*2);
  unsigned short* ybuf = (unsigned short*)alloc((size_t)NPAIR*HD*2);
  int*   tki   = (int*)alloc((size_t)T_TOK*TOPK*4);
  float* tkw   = (float*)alloc((size_t)T_TOK*TOPK*4);
  int*   rowsb = (int*)alloc((size_t)NPAIR*4);
  int*   slotf = (int*)alloc((size_t)NPAIR*4);
  int*   cntb  = (int*)alloc(NE*4);
  int*   offsb = (int*)alloc(NE*4);

  const int n4 = NE*FF*HD/4;
  convert_bf16_kernel<<<4096, 256, 0, stream>>>(gw, gwb, n4);
  convert_bf16_kernel<<<4096, 256, 0, stream>>>(uw, uwb, n4);
  convert_bf16_kernel<<<4096, 256, 0, stream>>>(dw, dwb, n4);

  router_kernel<<<T_TOK, 256, 0, stream>>>(x, rw, xbf, tki, tkw);
  count_kernel<<<NE, 256, 0, stream>>>(tki, cntb);
  lists_kernel<<<NE, 256, 0, stream>>>(tki, cntb, rowsb, slotf, offsb);

  (void)hipFuncSetAttribute((const void*)gemm_gateup8,
      hipFuncAttributeMaxDynamicSharedMemorySize, 131072);
  (void)hipFuncSetAttribute((const void*)gemm_down8,
      hipFuncAttributeMaxDynamicSharedMemorySize, 131072);

  gemm_gateup8<<<16*(FF/128)*NE, 512, 131072, stream>>>(xbf, gwb, uwb, rowsb, cntb, offsb, hbuf);
  gemm_down8<<<16*(HD/256)*NE, 512, 131072, stream>>>(hbuf, dwb, cntb, offsb, ybuf);

  combine_kernel<<<T_TOK, 256, 0, stream>>>(ybuf, slotf, tkw, out);
}

// Round 5
// 859.237 us; speedup vs baseline: 1.1548x; 1.1548x over previous
//
#include <hip/hip_runtime.h>
#include <hip/hip_bf16.h>
#include <stdint.h>
#include <math.h>

#define T_TOK 4096
#define HD    1024
#define NE    16
#define FF    2816
#define TOPK  8
#define NPAIR (T_TOK*TOPK)

typedef __attribute__((ext_vector_type(8))) __bf16 bf16x8;
typedef __attribute__((ext_vector_type(4))) float  f32x4;

__device__ __forceinline__ unsigned short f2bf(float x){
  union { float f; unsigned u; } c; c.f = x;
  unsigned r = (c.u + 0x7FFFu + ((c.u >> 16) & 1u)) >> 16;
  return (unsigned short)r;
}
__device__ __forceinline__ float bf2f(unsigned short h){
  union { unsigned u; float f; } c; c.u = ((unsigned)h) << 16; return c.f;
}

// async global->LDS, 16B per lane
__device__ __forceinline__ void gload16(const void* src, void* lds_dst){
  __builtin_amdgcn_global_load_lds((const __attribute__((address_space(1))) unsigned int*)src,
                                   (__attribute__((address_space(3))) unsigned int*)lds_dst,
                                   16, 0, 0);
}

// ---------------- fused fp32 -> bf16 (RNE) conversion of all 3 weight tensors ----------------
__global__ __launch_bounds__(256) void convert3_kernel(
    const float* __restrict__ g, const float* __restrict__ u, const float* __restrict__ d,
    unsigned short* __restrict__ gb, unsigned short* __restrict__ ub, unsigned short* __restrict__ db,
    int n4each)
{
  int i = blockIdx.x * blockDim.x + threadIdx.x;
  int stride = gridDim.x * blockDim.x;
  int total = 3 * n4each;
  for (; i < total; i += stride){
    const float* s; unsigned short* dst; int j;
    if (i < n4each){ s = g; dst = gb; j = i; }
    else if (i < 2*n4each){ s = u; dst = ub; j = i - n4each; }
    else { s = d; dst = db; j = i - 2*n4each; }
    float4 v = ((const float4*)s)[j];
    ushort4 o;
    o.x = f2bf(v.x); o.y = f2bf(v.y); o.z = f2bf(v.z); o.w = f2bf(v.w);
    ((ushort4*)dst)[j] = o;
  }
}

// ---------------- router ----------------
__global__ __launch_bounds__(256) void router_kernel(
    const float* __restrict__ x, const float* __restrict__ rw,
    unsigned short* __restrict__ xbf, int* __restrict__ topk_idx, float* __restrict__ topk_w)
{
  __shared__ float xs[HD];
  __shared__ float lg[NE];
  const int t   = blockIdx.x;
  const int tid = threadIdx.x;
  const int lane = tid & 63;
  const int wid  = tid >> 6;

  float4 v = ((const float4*)(x + (size_t)t*HD))[tid];
  ((float4*)xs)[tid] = v;
  ushort4 o;
  o.x = f2bf(v.x); o.y = f2bf(v.y); o.z = f2bf(v.z); o.w = f2bf(v.w);
  ((ushort4*)(xbf + (size_t)t*HD))[tid] = o;
  __syncthreads();

  for (int ee = 0; ee < 4; ++ee){
    int e = wid*4 + ee;
    const float* w = rw + (size_t)e*HD;
    float p = 0.f;
    for (int j = lane; j < HD; j += 64) p += xs[j] * w[j];
    #pragma unroll
    for (int offs = 32; offs; offs >>= 1) p += __shfl_xor(p, offs, 64);
    if (lane == 0) lg[e] = p;
  }
  __syncthreads();

  if (tid == 0){
    float vals[NE];
    #pragma unroll
    for (int e = 0; e < NE; ++e) vals[e] = lg[e];
    int   idx[TOPK]; float tv[TOPK];
    for (int k = 0; k < TOPK; ++k){
      int bi = 0; float bv = -3.4e38f;
      for (int e = 0; e < NE; ++e) if (vals[e] > bv){ bv = vals[e]; bi = e; }
      idx[k] = bi; tv[k] = bv; vals[bi] = -3.4e38f;
    }
    float m = tv[0];
    float ex[TOPK]; float s = 0.f;
    for (int k = 0; k < TOPK; ++k){ ex[k] = expf(tv[k] - m); s += ex[k]; }
    float inv = 1.f / s;
    for (int k = 0; k < TOPK; ++k){
      topk_idx[t*TOPK + k] = idx[k];
      topk_w [t*TOPK + k] = ex[k] * inv;
    }
  }
}

// ---------------- deterministic token lists (self-sufficient: derives cnt+offs) ----------------
__global__ __launch_bounds__(256) void lists_kernel(
    const int* __restrict__ topk_idx,
    int* __restrict__ rows, int* __restrict__ slot_of,
    int* __restrict__ cnt, int* __restrict__ offs_out)
{
  const int e = blockIdx.x;
  const int tid = threadIdx.x;
  const int lane = tid & 63;
  const int wid  = tid >> 6;

  __shared__ int wred[4];
  __shared__ int wred2[4];
  __shared__ int soff;

  // pass 1: off = #entries < e over all tokens; c = #entries == e
  int nlt = 0, ceq = 0;
  for (int t = tid; t < T_TOK; t += 256){
    #pragma unroll
    for (int k = 0; k < TOPK; ++k){
      int vv = topk_idx[t*TOPK + k];
      nlt += (vv < e) ? 1 : 0;
      ceq += (vv == e) ? 1 : 0;
    }
  }
  #pragma unroll
  for (int offs = 32; offs; offs >>= 1){
    nlt += __shfl_xor(nlt, offs, 64);
    ceq += __shfl_xor(ceq, offs, 64);
  }
  if (lane == 0){ wred[wid] = nlt; wred2[wid] = ceq; }
  __syncthreads();
  if (tid == 0){
    int off = wred[0] + wred[1] + wred[2] + wred[3];
    int c   = wred2[0] + wred2[1] + wred2[2] + wred2[3];
    offs_out[e] = off;
    cnt[e] = c;
    soff = off;
  }
  __syncthreads();
  const int off = soff;

  // pass 2: stable placement
  __shared__ int wc[4];
  int base = 0;
  for (int c0 = 0; c0 < T_TOK; c0 += 256){
    int t = c0 + tid;
    int kpos = -1;
    #pragma unroll
    for (int k = 0; k < TOPK; ++k) if (topk_idx[t*TOPK + k] == e) kpos = k;
    bool f = (kpos >= 0);
    unsigned long long m = __ballot(f);
    if (lane == 0) wc[wid] = __popcll(m);
    __syncthreads();
    int p = base;
    for (int w = 0; w < wid; ++w) p += wc[w];
    p += __popcll(m & ((1ULL << lane) - 1ULL));
    if (f){
      rows[off + p] = t;
      slot_of[t*TOPK + kpos] = off + p;
    }
    int tot = wc[0] + wc[1] + wc[2] + wc[3];
    __syncthreads();
    base += tot;
  }
}

// ---------------- stage-1: h = silu(x@gateT) * (x@upT), grouped ----------------
// BM=128 (tokens) x BF=64, BK=64, 4 waves (2Mx2F, wave 64x32 each for g and u),
// single-buffered LDS (32KB, 3+ blocks/CU), m97-style 2-barrier loop,
// XOR-swizzled LDS rows (bank-conflict-free ds_read_b128).
__global__ __launch_bounds__(256, 3) void gemm_gateup(
    const unsigned short* __restrict__ xbf,
    const unsigned short* __restrict__ gw,
    const unsigned short* __restrict__ uw,
    const int* __restrict__ rows, const int* __restrict__ cnt, const int* __restrict__ offs,
    unsigned short* __restrict__ hbuf)
{
  // 1D grid = 32 * (FF/64) * NE, bijective XCD swizzle (grid % 8 == 0)
  const int cpx = gridDim.x >> 3;
  const int bid = blockIdx.x;
  const int nid = (bid & 7) * cpx + (bid >> 3);
  const int mb   = nid & 31;
  const int rest = nid >> 5;
  const int nb   = rest % (FF/64);
  const int e    = rest / (FF/64);

  const int c  = cnt[e];
  const int m0 = mb * 128;
  if (m0 >= c) return;
  const int n0 = nb * 64;
  const int off_e = offs[e];

  __shared__ unsigned short As[128*64];
  __shared__ unsigned short Bg[64*64];
  __shared__ unsigned short Bu[64*64];

  const int tid  = threadIdx.x;
  const int lane = tid & 63;
  const int wid  = tid >> 6;
  const int ar = lane & 15;
  const int kb = lane >> 4;
  const int wm = wid >> 1;
  const int wn = wid & 1;

  // chunk c = j*256+tid -> row c>>3, phys slot c&7; phys slot holds logical (c&7)^(row&7)
  const unsigned short* asrc[4];
  #pragma unroll
  for (int j = 0; j < 4; ++j){
    int cj = j*256 + tid;
    int r  = cj >> 3;
    int sw = ((cj & 7) ^ (r & 7)) * 8;
    int rm = m0 + r; if (rm > c-1) rm = c-1;
    asrc[j] = xbf + (size_t)rows[off_e + rm]*HD + sw;
  }
  const unsigned short* bgsrc[2];
  const unsigned short* busrc[2];
  #pragma unroll
  for (int j = 0; j < 2; ++j){
    int cj = j*256 + tid;
    int r  = cj >> 3;
    int sw = ((cj & 7) ^ (r & 7)) * 8;
    bgsrc[j] = gw + ((size_t)e*FF + n0 + r)*HD + sw;
    busrc[j] = uw + ((size_t)e*FF + n0 + r)*HD + sw;
  }

  f32x4 accg[4][2] = {};
  f32x4 accu[4][2] = {};

  for (int ks = 0; ks < HD/64; ++ks){
    #pragma unroll
    for (int j = 0; j < 4; ++j)
      gload16(asrc[j] + ks*64, &As[(j*256+tid)*8]);
    #pragma unroll
    for (int j = 0; j < 2; ++j){
      gload16(bgsrc[j] + ks*64, &Bg[(j*256+tid)*8]);
      gload16(busrc[j] + ks*64, &Bu[(j*256+tid)*8]);
    }
    __syncthreads();
    #pragma unroll
    for (int kk = 0; kk < 2; ++kk){
      bf16x8 a[4], fg[2], fu[2];
      #pragma unroll
      for (int m = 0; m < 4; ++m){
        int r = wm*64 + m*16 + ar;
        a[m] = *(const bf16x8*)&As[r*64 + (((kk*4 + kb) ^ (r & 7))*8)];
      }
      #pragma unroll
      for (int n = 0; n < 2; ++n){
        int rf = wn*32 + n*16 + ar;
        int o  = rf*64 + (((kk*4 + kb) ^ (rf & 7))*8);
        fg[n] = *(const bf16x8*)&Bg[o];
        fu[n] = *(const bf16x8*)&Bu[o];
      }
      #pragma unroll
      for (int m = 0; m < 4; ++m){
        #pragma unroll
        for (int n = 0; n < 2; ++n){
          accg[m][n] = __builtin_amdgcn_mfma_f32_16x16x32_bf16(a[m], fg[n], accg[m][n], 0, 0, 0);
          accu[m][n] = __builtin_amdgcn_mfma_f32_16x16x32_bf16(a[m], fu[n], accu[m][n], 0, 0, 0);
        }
      }
    }
    __syncthreads();
  }

  #pragma unroll
  for (int m = 0; m < 4; ++m){
    #pragma unroll
    for (int n = 0; n < 2; ++n){
      int fcol = n0 + wn*32 + n*16 + ar;
      #pragma unroll
      for (int i = 0; i < 4; ++i){
        int gr = m0 + wm*64 + m*16 + kb*4 + i;
        if (gr < c){
          float g = accg[m][n][i];
          float u = accu[m][n][i];
          float s = g / (1.0f + expf(-g));
          hbuf[(size_t)(off_e + gr)*FF + fcol] = f2bf(s * u);
        }
      }
    }
  }
}

// ---------------- stage-2: y = h @ downT, grouped ----------------
// BM=128 x BN=128, BK=64, 4 waves (2x2, wave 64x64), same structure.
__global__ __launch_bounds__(256, 3) void gemm_down(
    const unsigned short* __restrict__ hbuf,
    const unsigned short* __restrict__ dw,
    const int* __restrict__ cnt, const int* __restrict__ offs,
    unsigned short* __restrict__ ybuf)
{
  // 1D grid = 32 * (HD/128) * NE = 4096, XCD swizzle
  const int cpx = gridDim.x >> 3;
  const int bid = blockIdx.x;
  const int nid = (bid & 7) * cpx + (bid >> 3);
  const int mb   = nid & 31;
  const int rest = nid >> 5;
  const int nb   = rest & 7;
  const int e    = rest >> 3;

  const int c  = cnt[e];
  const int m0 = mb * 128;
  if (m0 >= c) return;
  const int n0 = nb * 128;
  const int off_e = offs[e];

  __shared__ unsigned short As[128*64];
  __shared__ unsigned short Bs[128*64];

  const int tid  = threadIdx.x;
  const int lane = tid & 63;
  const int wid  = tid >> 6;
  const int ar = lane & 15;
  const int kb = lane >> 4;
  const int wm = wid >> 1;
  const int wn = wid & 1;

  const unsigned short* asrc[4];
  const unsigned short* bsrc[4];
  #pragma unroll
  for (int j = 0; j < 4; ++j){
    int cj = j*256 + tid;
    int r  = cj >> 3;
    int sw = ((cj & 7) ^ (r & 7)) * 8;
    int rm = m0 + r; if (rm > c-1) rm = c-1;
    asrc[j] = hbuf + (size_t)(off_e + rm)*FF + sw;
    bsrc[j] = dw + ((size_t)e*HD + n0 + r)*FF + sw;
  }

  f32x4 acc[4][4] = {};

  for (int ks = 0; ks < FF/64; ++ks){
    #pragma unroll
    for (int j = 0; j < 4; ++j){
      gload16(asrc[j] + ks*64, &As[(j*256+tid)*8]);
      gload16(bsrc[j] + ks*64, &Bs[(j*256+tid)*8]);
    }
    __syncthreads();
    #pragma unroll
    for (int kk = 0; kk < 2; ++kk){
      bf16x8 a[4], b[4];
      #pragma unroll
      for (int m = 0; m < 4; ++m){
        int r = wm*64 + m*16 + ar;
        a[m] = *(const bf16x8*)&As[r*64 + (((kk*4 + kb) ^ (r & 7))*8)];
      }
      #pragma unroll
      for (int n = 0; n < 4; ++n){
        int r = wn*64 + n*16 + ar;
        b[n] = *(const bf16x8*)&Bs[r*64 + (((kk*4 + kb) ^ (r & 7))*8)];
      }
      #pragma unroll
      for (int m = 0; m < 4; ++m){
        #pragma unroll
        for (int n = 0; n < 4; ++n){
          acc[m][n] = __builtin_amdgcn_mfma_f32_16x16x32_bf16(a[m], b[n], acc[m][n], 0, 0, 0);
        }
      }
    }
    __syncthreads();
  }

  #pragma unroll
  for (int m = 0; m < 4; ++m){
    #pragma unroll
    for (int n = 0; n < 4; ++n){
      int col = n0 + wn*64 + n*16 + ar;
      #pragma unroll
      for (int i = 0; i < 4; ++i){
        int gr = m0 + wm*64 + m*16 + kb*4 + i;
        if (gr < c){
          ybuf[(size_t)(off_e + gr)*HD + col] = f2bf(acc[m][n][i]);
        }
      }
    }
  }
}

// ---------------- combine ----------------
__global__ __launch_bounds__(256) void combine_kernel(
    const unsigned short* __restrict__ ybuf,
    const int* __restrict__ slot_of, const float* __restrict__ topk_w,
    float* __restrict__ out)
{
  const int t   = blockIdx.x;
  const int tid = threadIdx.x;
  const int c0  = tid * 4;
  float4 acc = {0.f, 0.f, 0.f, 0.f};
  #pragma unroll
  for (int k = 0; k < TOPK; ++k){
    int slot = slot_of[t*TOPK + k];
    float w  = topk_w[t*TOPK + k];
    ushort4 v = *(const ushort4*)&ybuf[(size_t)slot*HD + c0];
    acc.x += w * bf2f(v.x);
    acc.y += w * bf2f(v.y);
    acc.z += w * bf2f(v.z);
    acc.w += w * bf2f(v.w);
  }
  ((float4*)out)[(size_t)t*(HD/4) + tid] = acc;
}

extern "C" void kernel_launch(void* const* d_in, const int* in_sizes, int n_in,
                              void* d_out, int out_size, void* d_ws, size_t ws_size,
                              hipStream_t stream)
{
  const float* x  = (const float*)d_in[0];
  const float* rw = (const float*)d_in[1];
  const float* gw = (const float*)d_in[2];
  const float* uw = (const float*)d_in[3];
  const float* dw = (const float*)d_in[4];
  float* out = (float*)d_out;

  char* ws = (char*)d_ws;
  size_t off = 0;
  auto alloc = [&](size_t b) -> void* {
    void* p = ws + off;
    off += (b + 255) & ~(size_t)255;
    return p;
  };

  unsigned short* gwb  = (unsigned short*)alloc((size_t)NE*FF*HD*2);
  unsigned short* uwb  = (unsigned short*)alloc((size_t)NE*FF*HD*2);
  unsigned short* dwb  = (unsigned short*)alloc((size_t)NE*HD*FF*2);
  unsigned short* xbf  = (unsigned short*)alloc((size_t)T_TOK*HD*2);
  unsigned short* hbuf = (unsigned short*)alloc((size_t)NPAIR*FF*2);
  unsigned short* ybuf = (unsigned short*)alloc((size_t)NPAIR*HD*2);
  int*   tki   = (int*)alloc((size_t)T_TOK*TOPK*4);
  float* tkw   = (float*)alloc((size_t)T_TOK*TOPK*4);
  int*   rowsb = (int*)alloc((size_t)NPAIR*4);
  int*   slotf = (int*)alloc((size_t)NPAIR*4);
  int*   cntb  = (int*)alloc(NE*4);
  int*   offsb = (int*)alloc(NE*4);

  const int n4 = NE*FF*HD/4;
  convert3_kernel<<<4096, 256, 0, stream>>>(gw, uw, dw, gwb, uwb, dwb, n4);

  router_kernel<<<T_TOK, 256, 0, stream>>>(x, rw, xbf, tki, tkw);
  lists_kernel<<<NE, 256, 0, stream>>>(tki, rowsb, slotf, cntb, offsb);

  gemm_gateup<<<32*(FF/64)*NE, 256, 0, stream>>>(xbf, gwb, uwb, rowsb, cntb, offsb, hbuf);
  gemm_down<<<32*(HD/128)*NE, 256, 0, stream>>>(hbuf, dwb, cntb, offsb, ybuf);

  combine_kernel<<<T_TOK, 256, 0, stream>>>(ybuf, slotf, tkw, out);
}